// Round 7
// baseline (68.860 us; speedup 1.0000x reference)
//
#include <hip/hip_runtime.h>
#include <hip/hip_bf16.h>

// Problem constants (B=8, S=512, D=256, M=64, DE=256, H=8, DH=32).
// entity_mask == 0 always (softmax rows sum to 1 -> activity = 1/512 < 0.1),
// so graph output is exactly zero; only `entities` needs compute.
//
// Round 7: fuse combine8 + wo-GEMM into one barrier-free kernel (wo_fused):
// phase1 combines the 8 attention partials straight into LDS as bf16 hi/lo
// (A) and preloads transposed wo hi/lo (B); phase2 = 96 MFMAs, no barriers.
// 4 dispatches total: preproc, gemm_kv, attn_stage, wo_fused.

typedef unsigned short ushort_t;
typedef __attribute__((ext_vector_type(8))) short short8;
typedef __attribute__((ext_vector_type(4))) float f32x4;

__device__ __forceinline__ ushort_t f2bf(float f) {
    unsigned u = __builtin_bit_cast(unsigned, f);
    unsigned r = (u + 0x7fff + ((u >> 16) & 1)) >> 16;   // RNE
    return (ushort_t)r;
}
__device__ __forceinline__ float bf2f(ushort_t h) {
    return __builtin_bit_cast(float, (unsigned)h << 16);
}

// ---------------- P: fused preprocessing ----------------
// [0,1024):    x = emb+pos -> xh/xl
// [1024,1536): wk|wv -> bh/bl [256][512] hi/lo
// [1536,1792): wo -> wt_h/wt_l TRANSPOSED [n][k] hi/lo (16x16 tiles)
// [1792,1856): qproj
// [1856,1889): zero graph+mask tail of d_out
__global__ __launch_bounds__(256) void preproc_kernel(
        const float* __restrict__ emb, const float* __restrict__ pos,
        const float* __restrict__ wk, const float* __restrict__ wv,
        const float* __restrict__ wo, const float* __restrict__ lib,
        const float* __restrict__ wq,
        ushort_t* __restrict__ xh, ushort_t* __restrict__ xl,
        ushort_t* __restrict__ bh, ushort_t* __restrict__ bl,
        ushort_t* __restrict__ wt_h, ushort_t* __restrict__ wt_l,
        float* __restrict__ qbuf, float4* __restrict__ tail) {
    __shared__ float sh[256];
    __shared__ ushort_t th[16][17], tl[16][17];
    const int blk = blockIdx.x, tid = threadIdx.x;
    if (blk < 1024) {
        int i = blk * 256 + tid;
        int dq = i & 63, s = (i >> 6) & 511;
        float4 e = ((const float4*)emb)[i];
        float4 p = ((const float4*)pos)[(s << 6) + dq];
        float v[4] = {e.x + p.x, e.y + p.y, e.z + p.z, e.w + p.w};
        ushort_t h0 = f2bf(v[0]), h1 = f2bf(v[1]), h2 = f2bf(v[2]), h3 = f2bf(v[3]);
        ushort_t l0 = f2bf(v[0] - bf2f(h0)), l1 = f2bf(v[1] - bf2f(h1));
        ushort_t l2 = f2bf(v[2] - bf2f(h2)), l3 = f2bf(v[3] - bf2f(h3));
        ((uint2*)xh)[i] = make_uint2((unsigned)h0 | ((unsigned)h1 << 16),
                                     (unsigned)h2 | ((unsigned)h3 << 16));
        ((uint2*)xl)[i] = make_uint2((unsigned)l0 | ((unsigned)l1 << 16),
                                     (unsigned)l2 | ((unsigned)l3 << 16));
    } else if (blk < 1536) {
        int idx = (blk - 1024) * 256 + tid;          // 131072
        int row = idx >> 9, col = idx & 511;
        float v = (col < 256) ? wk[row * 256 + col] : wv[row * 256 + col - 256];
        ushort_t h = f2bf(v);
        bh[idx] = h;
        bl[idx] = f2bf(v - bf2f(h));
    } else if (blk < 1792) {
        // transpose wo [k][n] -> wt [n][k], 16x16 tiles, hi/lo split
        int tt = blk - 1536;                          // 0..255
        int kt = tt >> 4, nt = tt & 15;
        int r = tid >> 4, c = tid & 15;
        float v = wo[(size_t)(kt * 16 + r) * 256 + nt * 16 + c];
        ushort_t h = f2bf(v);
        th[r][c] = h;
        tl[r][c] = f2bf(v - bf2f(h));
        __syncthreads();
        int c2 = tid >> 4, r2 = tid & 15;
        size_t o = (size_t)(nt * 16 + c2) * 256 + kt * 16 + r2;
        wt_h[o] = th[r2][c2];
        wt_l[o] = tl[r2][c2];
    } else if (blk < 1856) {
        int m = blk - 1792;
        sh[tid] = lib[m * 256 + tid];
        __syncthreads();
        float acc = 0.f;
        #pragma unroll 8
        for (int d = 0; d < 256; ++d) acc = fmaf(sh[d], wq[d * 256 + tid], acc);
        qbuf[m * 256 + tid] = acc * 0.17677669529663687f;   // 1/sqrt(32)
    } else {
        int i = (blk - 1856) * 256 + tid;
        if (i < 8320) tail[i] = make_float4(0.f, 0.f, 0.f, 0.f);
    }
}

// ---------------- split-bf16 MFMA GEMM (K|V projection) ----------------
// C[*,512] = A[*,256] @ B[256,512]; 3 terms Ah*Bh + Al*Bh + Ah*Bl.
// BM=128, BN=64, BK=32; cols [0,256)->out0, [256,512)->out1.
__global__ __launch_bounds__(256) void gemm_split_mfma_kernel(
        const ushort_t* __restrict__ Ah, const ushort_t* __restrict__ Al,
        const ushort_t* __restrict__ Bh, const ushort_t* __restrict__ Bl,
        float* __restrict__ out0, float* __restrict__ out1, int N) {
    __shared__ ushort_t As[128][40];
    __shared__ ushort_t Bs[64][40];
    const int tid = threadIdx.x;
    const int w = tid >> 6, l = tid & 63;
    const int wr = w >> 1, wc = w & 1;
    const int m0 = blockIdx.x * 128;
    const int n0 = blockIdx.y * 64;
    const int l15 = l & 15, lk8 = (l >> 4) * 8;

    const ushort_t* Aseg[3] = {Ah, Al, Ah};
    const ushort_t* Bseg[3] = {Bh, Bh, Bl};

    f32x4 acc[4][2];
    #pragma unroll
    for (int i = 0; i < 4; ++i)
        #pragma unroll
        for (int j = 0; j < 2; ++j) acc[i][j] = (f32x4){0.f, 0.f, 0.f, 0.f};

    const int ar = tid >> 1, ah = (tid & 1) * 16;
    const int bn = tid & 63, bk = tid >> 6;

    short8 areg0, areg1;
    ushort_t breg[8];
    #define PRELOAD(st) do { \
        int seg = (st) >> 3, k0 = ((st) & 7) << 5; \
        const ushort_t* Ap = Aseg[seg] + (size_t)(m0 + ar) * 256 + k0 + ah; \
        areg0 = *(const short8*)Ap; \
        areg1 = *(const short8*)(Ap + 8); \
        const ushort_t* Bp = Bseg[seg] + (size_t)(k0 + bk * 8) * N + n0 + bn; \
        _Pragma("unroll") \
        for (int j = 0; j < 8; ++j) breg[j] = Bp[(size_t)j * N]; \
    } while (0)

    PRELOAD(0);
    for (int st = 0; st < 24; ++st) {
        __syncthreads();
        *(short8*)&As[ar][ah]     = areg0;
        *(short8*)&As[ar][ah + 8] = areg1;
        {
            short8 bv;
            #pragma unroll
            for (int j = 0; j < 8; ++j) bv[j] = (short)breg[j];
            *(short8*)&Bs[bn][bk * 8] = bv;
        }
        __syncthreads();
        if (st + 1 < 24) PRELOAD(st + 1);
        short8 a[4], b[2];
        #pragma unroll
        for (int i = 0; i < 4; ++i) a[i] = *(const short8*)&As[wr * 64 + i * 16 + l15][lk8];
        #pragma unroll
        for (int j = 0; j < 2; ++j) b[j] = *(const short8*)&Bs[wc * 32 + j * 16 + l15][lk8];
        #pragma unroll
        for (int i = 0; i < 4; ++i)
            #pragma unroll
            for (int j = 0; j < 2; ++j)
                acc[i][j] = __builtin_amdgcn_mfma_f32_16x16x32_bf16(a[i], b[j], acc[i][j], 0, 0, 0);
    }
    #undef PRELOAD

    float* outp = (n0 < 256) ? out0 : out1;
    const int nbase = (n0 < 256) ? n0 : (n0 - 256);
    #pragma unroll
    for (int i = 0; i < 4; ++i) {
        #pragma unroll
        for (int j = 0; j < 2; ++j) {
            int col = nbase + wc * 32 + j * 16 + l15;
            int rowb = m0 + wr * 64 + i * 16 + (l >> 4) * 4;
            #pragma unroll
            for (int r = 0; r < 4; ++r)
                outp[(size_t)(rowb + r) * 256 + col] = acc[i][j][r];
        }
    }
}

// ---------------- attention partials with LDS-staged K/V ----------------
// grid (64 bh, 8 sq); block covers 64 s-rows; 4 waves x 16 rows; lane = m.
__global__ __launch_bounds__(256) void attn_stage_kernel(const float* __restrict__ q,
        const float* __restrict__ k, const float* __restrict__ v,
        float* __restrict__ part) {
    __shared__ float sM[4][64], sS[4][64];
    __shared__ __align__(16) float big[9216];   // 36KB: stage 4096f | merge 4*64*36
    const int bh = blockIdx.x, sq = blockIdx.y;
    const int b = bh >> 3, h = bh & 7;
    const int tid = threadIdx.x;
    const int w = tid >> 6, m = tid & 63;
    const int s0b = sq * 64;

    {
        float4* Ks4 = (float4*)big;
        float4* Vs4 = Ks4 + 512;
        #pragma unroll
        for (int it = 0; it < 2; ++it) {
            int idx = it * 256 + tid;
            int row = idx >> 3, f4 = idx & 7;
            const float* kb = k + (size_t)(b * 512 + s0b + row) * 256 + h * 32;
            const float* vb = v + (size_t)(b * 512 + s0b + row) * 256 + h * 32;
            Ks4[idx] = ((const float4*)kb)[f4];
            Vs4[idx] = ((const float4*)vb)[f4];
        }
    }

    float qr[32];
    {
        const float4* qp = (const float4*)(q + m * 256 + h * 32);
        #pragma unroll
        for (int u = 0; u < 8; ++u) {
            float4 t4 = qp[u];
            qr[4*u] = t4.x; qr[4*u+1] = t4.y; qr[4*u+2] = t4.z; qr[4*u+3] = t4.w;
        }
    }
    __syncthreads();

    const float* Ks = big;
    const float* Vs = big + 2048;
    float Mx = -1e30f, sum = 0.f, acc[32];
    #pragma unroll
    for (int dh = 0; dh < 32; ++dh) acc[dh] = 0.f;

    #pragma unroll
    for (int cc = 0; cc < 2; ++cc) {
        float sc[8];
        #pragma unroll
        for (int i = 0; i < 8; ++i) {
            const float4* kr = (const float4*)&Ks[(size_t)(w * 16 + cc * 8 + i) * 32];
            float d0 = 0.f, d1 = 0.f, d2 = 0.f, d3 = 0.f;
            #pragma unroll
            for (int u = 0; u < 8; ++u) {
                float4 kv = kr[u];
                d0 = fmaf(qr[4*u],   kv.x, d0);
                d1 = fmaf(qr[4*u+1], kv.y, d1);
                d2 = fmaf(qr[4*u+2], kv.z, d2);
                d3 = fmaf(qr[4*u+3], kv.w, d3);
            }
            sc[i] = (d0 + d1) + (d2 + d3);
        }
        float cm = sc[0];
        #pragma unroll
        for (int i = 1; i < 8; ++i) cm = fmaxf(cm, sc[i]);
        float nm = fmaxf(Mx, cm);
        float f = __expf(Mx - nm);
        sum *= f;
        #pragma unroll
        for (int dh = 0; dh < 32; ++dh) acc[dh] *= f;
        #pragma unroll
        for (int i = 0; i < 8; ++i) {
            float p = __expf(sc[i] - nm);
            sum += p;
            const float4* vr = (const float4*)&Vs[(size_t)(w * 16 + cc * 8 + i) * 32];
            #pragma unroll
            for (int u = 0; u < 8; ++u) {
                float4 vv = vr[u];
                acc[4*u]   = fmaf(p, vv.x, acc[4*u]);
                acc[4*u+1] = fmaf(p, vv.y, acc[4*u+1]);
                acc[4*u+2] = fmaf(p, vv.z, acc[4*u+2]);
                acc[4*u+3] = fmaf(p, vv.w, acc[4*u+3]);
            }
        }
        Mx = nm;
    }
    __syncthreads();

    sM[w][m] = Mx; sS[w][m] = sum;
    float* sAcc = big;  // [4][64][36]
    #pragma unroll
    for (int u = 0; u < 8; ++u)
        *(float4*)&sAcc[(size_t)(w * 64 + m) * 36 + 4 * u] =
            make_float4(acc[4*u], acc[4*u+1], acc[4*u+2], acc[4*u+3]);
    __syncthreads();

    const int mm = tid >> 2, g = tid & 3;
    float Mj[4];
    float Mg = -1e30f;
    #pragma unroll
    for (int j = 0; j < 4; ++j) { Mj[j] = sM[j][mm]; Mg = fmaxf(Mg, Mj[j]); }
    float wgt[4]; float Ssum = 0.f;
    #pragma unroll
    for (int j = 0; j < 4; ++j) { wgt[j] = __expf(Mj[j] - Mg); Ssum = fmaf(wgt[j], sS[j][mm], Ssum); }
    float* rec = part + ((size_t)(bh * 8 + sq) * 64 + mm) * 36;
    #pragma unroll
    for (int uq = 0; uq < 2; ++uq) {
        float o[4];
        #pragma unroll
        for (int u = 0; u < 4; ++u) {
            int dh = g * 8 + uq * 4 + u;
            float num = 0.f;
            #pragma unroll
            for (int j = 0; j < 4; ++j) num = fmaf(wgt[j], sAcc[(size_t)(j * 64 + mm) * 36 + dh], num);
            o[u] = num;
        }
        *(float4*)(rec + g * 8 + uq * 4) = make_float4(o[0], o[1], o[2], o[3]);
    }
    if (g == 0) { rec[32] = Mg; rec[33] = Ssum; }
}

// ---------------- fused combine + wo GEMM ----------------
// grid (8 b, 4 n-tiles of 64). Phase1: combine 8 partials -> A = ctx[b] rows
// 64 x 256 as bf16 hi/lo in LDS; preload B = wo^T hi/lo cols n0..n0+63 in LDS.
// Phase2 (after ONE barrier): 3-segment split GEMM, 96 MFMA, barrier-free.
__global__ __launch_bounds__(256) void wo_fused_kernel(const float* __restrict__ part,
        const ushort_t* __restrict__ wt_h, const ushort_t* __restrict__ wt_l,
        float* __restrict__ out) {
    __shared__ ushort_t AhL[64][264], AlL[64][264];   // 33792 B each
    __shared__ ushort_t BhL[64][264], BlL[64][264];   // total 132 KB
    const int b = blockIdx.x;
    const int n0 = blockIdx.y * 64;
    const int tid = threadIdx.x;

    // ---- phase 1a: combine partials -> ctx rows (bf16 hi/lo) ----
    {
        const int hd = tid >> 5, mb = tid & 31;
        const size_t js = (size_t)64 * 36;   // j stride in floats
        #pragma unroll
        for (int half = 0; half < 2; ++half) {
            const int m = mb + half * 32;
            const float* rec = part + ((size_t)((b * 8 + hd) * 8) * 64 + m) * 36;
            float Mj[8], Sj[8];
            float Mg = -1e30f;
            #pragma unroll
            for (int j = 0; j < 8; ++j) {
                Mj[j] = rec[j * js + 32];
                Sj[j] = rec[j * js + 33];
                Mg = fmaxf(Mg, Mj[j]);
            }
            float wgt[8]; float Ssum = 0.f;
            #pragma unroll
            for (int j = 0; j < 8; ++j) { wgt[j] = __expf(Mj[j] - Mg); Ssum = fmaf(wgt[j], Sj[j], Ssum); }
            const float inv = 1.f / Ssum;
            #pragma unroll
            for (int dq = 0; dq < 8; ++dq) {
                float a0 = 0.f, a1 = 0.f, a2 = 0.f, a3 = 0.f;
                #pragma unroll
                for (int j = 0; j < 8; ++j) {
                    const float4 vv = *(const float4*)(rec + j * js + dq * 4);
                    a0 = fmaf(wgt[j], vv.x, a0);
                    a1 = fmaf(wgt[j], vv.y, a1);
                    a2 = fmaf(wgt[j], vv.z, a2);
                    a3 = fmaf(wgt[j], vv.w, a3);
                }
                a0 *= inv; a1 *= inv; a2 *= inv; a3 *= inv;
                ushort_t h0 = f2bf(a0), h1 = f2bf(a1), h2 = f2bf(a2), h3 = f2bf(a3);
                ushort_t q0 = f2bf(a0 - bf2f(h0)), q1 = f2bf(a1 - bf2f(h1));
                ushort_t q2 = f2bf(a2 - bf2f(h2)), q3 = f2bf(a3 - bf2f(h3));
                *(uint2*)&AhL[m][hd * 32 + dq * 4] =
                    make_uint2((unsigned)h0 | ((unsigned)h1 << 16), (unsigned)h2 | ((unsigned)h3 << 16));
                *(uint2*)&AlL[m][hd * 32 + dq * 4] =
                    make_uint2((unsigned)q0 | ((unsigned)q1 << 16), (unsigned)q2 | ((unsigned)q3 << 16));
            }
        }
    }

    // ---- phase 1b: preload B = wo^T hi/lo ----
    {
        const int n = tid >> 2, kq = (tid & 3) * 64;
        const ushort_t* sh_ = wt_h + (size_t)(n0 + n) * 256 + kq;
        const ushort_t* sl_ = wt_l + (size_t)(n0 + n) * 256 + kq;
        #pragma unroll
        for (int s8 = 0; s8 < 8; ++s8) {
            *(short8*)&BhL[n][kq + s8 * 8] = *(const short8*)(sh_ + s8 * 8);
            *(short8*)&BlL[n][kq + s8 * 8] = *(const short8*)(sl_ + s8 * 8);
        }
    }
    __syncthreads();

    // ---- phase 2: 3-segment split GEMM from LDS, no barriers ----
    const int w = tid >> 6, l = tid & 63;
    const int wr = w >> 1, wc = w & 1;
    const int l15 = l & 15, lk8 = (l >> 4) * 8;
    f32x4 acc[2][2];
    #pragma unroll
    for (int i = 0; i < 2; ++i)
        #pragma unroll
        for (int j = 0; j < 2; ++j) acc[i][j] = (f32x4){0.f, 0.f, 0.f, 0.f};

    #pragma unroll
    for (int seg = 0; seg < 3; ++seg) {
        const ushort_t (*Ap)[264] = (seg == 1) ? AlL : AhL;
        const ushort_t (*Bp)[264] = (seg == 2) ? BlL : BhL;
        #pragma unroll
        for (int kf = 0; kf < 8; ++kf) {
            const int k0 = kf * 32 + lk8;
            short8 a0 = *(const short8*)&Ap[wr * 32 + l15][k0];
            short8 a1 = *(const short8*)&Ap[wr * 32 + 16 + l15][k0];
            short8 b0 = *(const short8*)&Bp[wc * 32 + l15][k0];
            short8 b1 = *(const short8*)&Bp[wc * 32 + 16 + l15][k0];
            acc[0][0] = __builtin_amdgcn_mfma_f32_16x16x32_bf16(a0, b0, acc[0][0], 0, 0, 0);
            acc[0][1] = __builtin_amdgcn_mfma_f32_16x16x32_bf16(a0, b1, acc[0][1], 0, 0, 0);
            acc[1][0] = __builtin_amdgcn_mfma_f32_16x16x32_bf16(a1, b0, acc[1][0], 0, 0, 0);
            acc[1][1] = __builtin_amdgcn_mfma_f32_16x16x32_bf16(a1, b1, acc[1][1], 0, 0, 0);
        }
    }

    // C/D layout: col=lane&15, row=(lane>>4)*4+reg [m89-verified]
    #pragma unroll
    for (int i = 0; i < 2; ++i) {
        #pragma unroll
        for (int j = 0; j < 2; ++j) {
            int col = n0 + wc * 32 + j * 16 + l15;
            int rowb = b * 64 + wr * 32 + i * 16 + (l >> 4) * 4;
            #pragma unroll
            for (int r = 0; r < 4; ++r)
                out[(size_t)(rowb + r) * 256 + col] = acc[i][j][r];
        }
    }
}

extern "C" void kernel_launch(void* const* d_in, const int* in_sizes, int n_in,
                              void* d_out, int out_size, void* d_ws, size_t ws_size,
                              hipStream_t stream) {
    const float* emb = (const float*)d_in[0];
    const float* lib = (const float*)d_in[2];
    const float* pos = (const float*)d_in[3];
    const float* wq  = (const float*)d_in[4];
    const float* wk  = (const float*)d_in[5];
    const float* wv  = (const float*)d_in[6];
    const float* wo  = (const float*)d_in[7];
    float* out = (float*)d_out;

    float* ws   = (float*)d_ws;
    float* kbuf = ws;                         // 1,048,576 f
    float* vbuf = kbuf + 1048576;             // 1,048,576 f
    float* qbuf = vbuf + 1048576;             // 16,384 f
    ushort_t* xh = (ushort_t*)(qbuf + 16384); // 1,048,576 us
    ushort_t* xl = xh + 1048576;              // 1,048,576 us
    ushort_t* bh = xl + 1048576;              // 131,072 us
    ushort_t* bl = bh + 131072;               // 131,072 us
    ushort_t* wt_h = bl + 131072;             // 65,536 us
    ushort_t* wt_l = wt_h + 65536;            // 65,536 us
    float* part = (float*)(wt_l + 65536);     // 1,179,648 f  (total ~17.5 MB)

    preproc_kernel<<<1889, 256, 0, stream>>>(emb, pos, wk, wv, wo, lib, wq,
            xh, xl, bh, bl, wt_h, wt_l, qbuf, (float4*)(out + 131072));

    gemm_split_mfma_kernel<<<dim3(32, 8), 256, 0, stream>>>(xh, xl, bh, bl, kbuf, vbuf, 512);

    attn_stage_kernel<<<dim3(64, 8), 256, 0, stream>>>(qbuf, kbuf, vbuf, part);

    wo_fused_kernel<<<dim3(8, 4), 256, 0, stream>>>(part, wt_h, wt_l, out);
}

// Round 8
// 60.422 us; speedup vs baseline: 1.1396x; 1.1396x over previous
//
#include <hip/hip_runtime.h>
#include <hip/hip_bf16.h>

// Problem constants (B=8, S=512, D=256, M=64, DE=256, H=8, DH=32).
// entity_mask == 0 always (softmax rows sum to 1 -> activity = 1/512 < 0.1),
// so graph output is exactly zero; only `entities` needs compute.
//
// Round 8: revert r7's wo fusion (occupancy-starved). New: barrier-free
// no-LDS direct-load MFMA GEMM — per-lane fragments are contiguous 16B runs
// in global when B is pre-transposed; K=256 is L2-resident, so stream
// fragments straight to MFMA. 5 dispatches: preproc, gemm_kv(direct),
// attn_stage, combine8, gemm_wo(direct).

typedef unsigned short ushort_t;
typedef __attribute__((ext_vector_type(8))) short short8;
typedef __attribute__((ext_vector_type(4))) float f32x4;

__device__ __forceinline__ ushort_t f2bf(float f) {
    unsigned u = __builtin_bit_cast(unsigned, f);
    unsigned r = (u + 0x7fff + ((u >> 16) & 1)) >> 16;   // RNE
    return (ushort_t)r;
}
__device__ __forceinline__ float bf2f(ushort_t h) {
    return __builtin_bit_cast(float, (unsigned)h << 16);
}

// ---------------- P: fused preprocessing ----------------
// [0,1024):    x = emb+pos -> xh/xl
// [1024,1536): wk|wv -> bt_h/bt_l TRANSPOSED [512 n][256 k] hi/lo
// [1536,1792): wo -> wt_h/wt_l TRANSPOSED [256 n][256 k] hi/lo
// [1792,1856): qproj
// [1856,1889): zero graph+mask tail of d_out
__global__ __launch_bounds__(256) void preproc_kernel(
        const float* __restrict__ emb, const float* __restrict__ pos,
        const float* __restrict__ wk, const float* __restrict__ wv,
        const float* __restrict__ wo, const float* __restrict__ lib,
        const float* __restrict__ wq,
        ushort_t* __restrict__ xh, ushort_t* __restrict__ xl,
        ushort_t* __restrict__ bt_h, ushort_t* __restrict__ bt_l,
        ushort_t* __restrict__ wt_h, ushort_t* __restrict__ wt_l,
        float* __restrict__ qbuf, float4* __restrict__ tail) {
    __shared__ float sh[256];
    __shared__ ushort_t th[16][17], tl[16][17];
    const int blk = blockIdx.x, tid = threadIdx.x;
    if (blk < 1024) {
        int i = blk * 256 + tid;
        int dq = i & 63, s = (i >> 6) & 511;
        float4 e = ((const float4*)emb)[i];
        float4 p = ((const float4*)pos)[(s << 6) + dq];
        float v[4] = {e.x + p.x, e.y + p.y, e.z + p.z, e.w + p.w};
        ushort_t h0 = f2bf(v[0]), h1 = f2bf(v[1]), h2 = f2bf(v[2]), h3 = f2bf(v[3]);
        ushort_t l0 = f2bf(v[0] - bf2f(h0)), l1 = f2bf(v[1] - bf2f(h1));
        ushort_t l2 = f2bf(v[2] - bf2f(h2)), l3 = f2bf(v[3] - bf2f(h3));
        ((uint2*)xh)[i] = make_uint2((unsigned)h0 | ((unsigned)h1 << 16),
                                     (unsigned)h2 | ((unsigned)h3 << 16));
        ((uint2*)xl)[i] = make_uint2((unsigned)l0 | ((unsigned)l1 << 16),
                                     (unsigned)l2 | ((unsigned)l3 << 16));
    } else if (blk < 1536) {
        // transpose [256 k][512 n] (wk|wv) -> bt [n][k], 16x16 tiles
        int tt = blk - 1024;                          // 0..511
        int kt = tt & 15, ntile = tt >> 4;            // 16 k-tiles, 32 n-tiles
        int r = tid >> 4, c = tid & 15;               // k-in-tile, n-in-tile
        int n = ntile * 16 + c, k = kt * 16 + r;
        float v = (n < 256) ? wk[(size_t)k * 256 + n] : wv[(size_t)k * 256 + n - 256];
        ushort_t h = f2bf(v);
        th[r][c] = h;
        tl[r][c] = f2bf(v - bf2f(h));
        __syncthreads();
        int c2 = tid >> 4, r2 = tid & 15;
        size_t o = (size_t)(ntile * 16 + c2) * 256 + kt * 16 + r2;
        bt_h[o] = th[r2][c2];
        bt_l[o] = tl[r2][c2];
    } else if (blk < 1792) {
        // transpose wo [256 k][256 n] -> wt [n][k], 16x16 tiles
        int tt = blk - 1536;                          // 0..255
        int kt = tt >> 4, nt = tt & 15;
        int r = tid >> 4, c = tid & 15;
        float v = wo[(size_t)(kt * 16 + r) * 256 + nt * 16 + c];
        ushort_t h = f2bf(v);
        th[r][c] = h;
        tl[r][c] = f2bf(v - bf2f(h));
        __syncthreads();
        int c2 = tid >> 4, r2 = tid & 15;
        size_t o = (size_t)(nt * 16 + c2) * 256 + kt * 16 + r2;
        wt_h[o] = th[r2][c2];
        wt_l[o] = tl[r2][c2];
    } else if (blk < 1856) {
        int m = blk - 1792;
        sh[tid] = lib[m * 256 + tid];
        __syncthreads();
        float acc = 0.f;
        #pragma unroll 8
        for (int d = 0; d < 256; ++d) acc = fmaf(sh[d], wq[d * 256 + tid], acc);
        qbuf[m * 256 + tid] = acc * 0.17677669529663687f;   // 1/sqrt(32)
    } else {
        int i = (blk - 1856) * 256 + tid;
        if (i < 8320) tail[i] = make_float4(0.f, 0.f, 0.f, 0.f);
    }
}

// ---------------- barrier-free direct-load split-bf16 MFMA GEMM ----------------
// C[M,256|512] = (Ah+Al)[M,256] @ (Bh+Bl)[256,N], B given TRANSPOSED [n][k].
// 3 split terms fused per kf: a_h*b_h + a_l*b_h + a_h*b_l.
// BM=128, BN=64; 4 waves (2x2); no LDS, no __syncthreads.
// Fragments are contiguous short8 runs: lane l -> row (tile + l&15),
// k = (l>>4)*8 + kf*32  [same mapping as the r4-verified LDS version].
__global__ __launch_bounds__(256) void gemm_direct_kernel(
        const ushort_t* __restrict__ Ah, const ushort_t* __restrict__ Al,
        const ushort_t* __restrict__ Bth, const ushort_t* __restrict__ Btl,
        float* __restrict__ out0, float* __restrict__ out1) {
    const int tid = threadIdx.x;
    const int w = tid >> 6, l = tid & 63;
    const int wr = w >> 1, wc = w & 1;
    const int m0 = blockIdx.x * 128;
    const int n0 = blockIdx.y * 64;
    const int l15 = l & 15, lk8 = (l >> 4) * 8;

    // preload B-hi fragments (reused 4x over i): 16 short8 = 64 VGPR
    short8 bhf[2][8];
    #pragma unroll
    for (int j = 0; j < 2; ++j) {
        const size_t base = (size_t)(n0 + wc * 32 + j * 16 + l15) * 256 + lk8;
        #pragma unroll
        for (int kf = 0; kf < 8; ++kf)
            bhf[j][kf] = *(const short8*)(Bth + base + kf * 32);
    }

    f32x4 acc[4][2];
    #pragma unroll
    for (int i = 0; i < 4; ++i)
        #pragma unroll
        for (int j = 0; j < 2; ++j) acc[i][j] = (f32x4){0.f, 0.f, 0.f, 0.f};

    #pragma unroll
    for (int kf = 0; kf < 8; ++kf) {
        short8 blf[2];
        #pragma unroll
        for (int j = 0; j < 2; ++j)
            blf[j] = *(const short8*)(Btl + (size_t)(n0 + wc * 32 + j * 16 + l15) * 256 + kf * 32 + lk8);
        #pragma unroll
        for (int i = 0; i < 4; ++i) {
            const size_t ab = (size_t)(m0 + wr * 64 + i * 16 + l15) * 256 + kf * 32 + lk8;
            short8 a_h = *(const short8*)(Ah + ab);
            short8 a_l = *(const short8*)(Al + ab);
            #pragma unroll
            for (int j = 0; j < 2; ++j) {
                acc[i][j] = __builtin_amdgcn_mfma_f32_16x16x32_bf16(a_h, bhf[j][kf], acc[i][j], 0, 0, 0);
                acc[i][j] = __builtin_amdgcn_mfma_f32_16x16x32_bf16(a_l, bhf[j][kf], acc[i][j], 0, 0, 0);
                acc[i][j] = __builtin_amdgcn_mfma_f32_16x16x32_bf16(a_h, blf[j], acc[i][j], 0, 0, 0);
            }
        }
    }

    // C/D layout: col=lane&15, row=(lane>>4)*4+reg [m89-verified]
    float* outp = (n0 < 256) ? out0 : out1;
    const int nbase = (n0 < 256) ? n0 : (n0 - 256);
    #pragma unroll
    for (int i = 0; i < 4; ++i) {
        #pragma unroll
        for (int j = 0; j < 2; ++j) {
            int col = nbase + wc * 32 + j * 16 + l15;
            int rowb = m0 + wr * 64 + i * 16 + (l >> 4) * 4;
            #pragma unroll
            for (int r = 0; r < 4; ++r)
                outp[(size_t)(rowb + r) * 256 + col] = acc[i][j][r];
        }
    }
}

// ---------------- attention partials with LDS-staged K/V ----------------
// grid (64 bh, 8 sq); block covers 64 s-rows; 4 waves x 16 rows; lane = m.
__global__ __launch_bounds__(256) void attn_stage_kernel(const float* __restrict__ q,
        const float* __restrict__ k, const float* __restrict__ v,
        float* __restrict__ part) {
    __shared__ float sM[4][64], sS[4][64];
    __shared__ __align__(16) float big[9216];   // 36KB: stage 4096f | merge 4*64*36
    const int bh = blockIdx.x, sq = blockIdx.y;
    const int b = bh >> 3, h = bh & 7;
    const int tid = threadIdx.x;
    const int w = tid >> 6, m = tid & 63;
    const int s0b = sq * 64;

    {
        float4* Ks4 = (float4*)big;
        float4* Vs4 = Ks4 + 512;
        #pragma unroll
        for (int it = 0; it < 2; ++it) {
            int idx = it * 256 + tid;
            int row = idx >> 3, f4 = idx & 7;
            const float* kb = k + (size_t)(b * 512 + s0b + row) * 256 + h * 32;
            const float* vb = v + (size_t)(b * 512 + s0b + row) * 256 + h * 32;
            Ks4[idx] = ((const float4*)kb)[f4];
            Vs4[idx] = ((const float4*)vb)[f4];
        }
    }

    float qr[32];
    {
        const float4* qp = (const float4*)(q + m * 256 + h * 32);
        #pragma unroll
        for (int u = 0; u < 8; ++u) {
            float4 t4 = qp[u];
            qr[4*u] = t4.x; qr[4*u+1] = t4.y; qr[4*u+2] = t4.z; qr[4*u+3] = t4.w;
        }
    }
    __syncthreads();

    const float* Ks = big;
    const float* Vs = big + 2048;
    float Mx = -1e30f, sum = 0.f, acc[32];
    #pragma unroll
    for (int dh = 0; dh < 32; ++dh) acc[dh] = 0.f;

    #pragma unroll
    for (int cc = 0; cc < 2; ++cc) {
        float sc[8];
        #pragma unroll
        for (int i = 0; i < 8; ++i) {
            const float4* kr = (const float4*)&Ks[(size_t)(w * 16 + cc * 8 + i) * 32];
            float d0 = 0.f, d1 = 0.f, d2 = 0.f, d3 = 0.f;
            #pragma unroll
            for (int u = 0; u < 8; ++u) {
                float4 kv = kr[u];
                d0 = fmaf(qr[4*u],   kv.x, d0);
                d1 = fmaf(qr[4*u+1], kv.y, d1);
                d2 = fmaf(qr[4*u+2], kv.z, d2);
                d3 = fmaf(qr[4*u+3], kv.w, d3);
            }
            sc[i] = (d0 + d1) + (d2 + d3);
        }
        float cm = sc[0];
        #pragma unroll
        for (int i = 1; i < 8; ++i) cm = fmaxf(cm, sc[i]);
        float nm = fmaxf(Mx, cm);
        float f = __expf(Mx - nm);
        sum *= f;
        #pragma unroll
        for (int dh = 0; dh < 32; ++dh) acc[dh] *= f;
        #pragma unroll
        for (int i = 0; i < 8; ++i) {
            float p = __expf(sc[i] - nm);
            sum += p;
            const float4* vr = (const float4*)&Vs[(size_t)(w * 16 + cc * 8 + i) * 32];
            #pragma unroll
            for (int u = 0; u < 8; ++u) {
                float4 vv = vr[u];
                acc[4*u]   = fmaf(p, vv.x, acc[4*u]);
                acc[4*u+1] = fmaf(p, vv.y, acc[4*u+1]);
                acc[4*u+2] = fmaf(p, vv.z, acc[4*u+2]);
                acc[4*u+3] = fmaf(p, vv.w, acc[4*u+3]);
            }
        }
        Mx = nm;
    }
    __syncthreads();

    sM[w][m] = Mx; sS[w][m] = sum;
    float* sAcc = big;  // [4][64][36]
    #pragma unroll
    for (int u = 0; u < 8; ++u)
        *(float4*)&sAcc[(size_t)(w * 64 + m) * 36 + 4 * u] =
            make_float4(acc[4*u], acc[4*u+1], acc[4*u+2], acc[4*u+3]);
    __syncthreads();

    const int mm = tid >> 2, g = tid & 3;
    float Mj[4];
    float Mg = -1e30f;
    #pragma unroll
    for (int j = 0; j < 4; ++j) { Mj[j] = sM[j][mm]; Mg = fmaxf(Mg, Mj[j]); }
    float wgt[4]; float Ssum = 0.f;
    #pragma unroll
    for (int j = 0; j < 4; ++j) { wgt[j] = __expf(Mj[j] - Mg); Ssum = fmaf(wgt[j], sS[j][mm], Ssum); }
    float* rec = part + ((size_t)(bh * 8 + sq) * 64 + mm) * 36;
    #pragma unroll
    for (int uq = 0; uq < 2; ++uq) {
        float o[4];
        #pragma unroll
        for (int u = 0; u < 4; ++u) {
            int dh = g * 8 + uq * 4 + u;
            float num = 0.f;
            #pragma unroll
            for (int j = 0; j < 4; ++j) num = fmaf(wgt[j], sAcc[(size_t)(j * 64 + mm) * 36 + dh], num);
            o[u] = num;
        }
        *(float4*)(rec + g * 8 + uq * 4) = make_float4(o[0], o[1], o[2], o[3]);
    }
    if (g == 0) { rec[32] = Mg; rec[33] = Ssum; }
}

// ---------------- combine 8 partials -> ctx bf16 hi/lo ----------------
__global__ __launch_bounds__(256) void attn_combine8_kernel(const float* __restrict__ part,
        ushort_t* __restrict__ ch, ushort_t* __restrict__ cl) {
    const int bh = blockIdx.x;
    const int b = bh >> 3, h = bh & 7;
    const int t = threadIdx.x;
    const int mm = t >> 2, g = t & 3;
    const float* pb = part + ((size_t)(bh * 8) * 64 + mm) * 36;
    float Mj[8], Sj[8];
    float Mg = -1e30f;
    #pragma unroll
    for (int j = 0; j < 8; ++j) {
        Mj[j] = pb[(size_t)j * 64 * 36 + 32];
        Sj[j] = pb[(size_t)j * 64 * 36 + 33];
        Mg = fmaxf(Mg, Mj[j]);
    }
    float wgt[8]; float Ssum = 0.f;
    #pragma unroll
    for (int j = 0; j < 8; ++j) { wgt[j] = __expf(Mj[j] - Mg); Ssum = fmaf(wgt[j], Sj[j], Ssum); }
    float inv = 1.f / Ssum;
    short8 hp, lp;
    #pragma unroll
    for (int u = 0; u < 8; ++u) {
        int dh = g * 8 + u;
        float num = 0.f;
        #pragma unroll
        for (int j = 0; j < 8; ++j) num = fmaf(wgt[j], pb[(size_t)j * 64 * 36 + dh], num);
        float val = num * inv;
        ushort_t hv = f2bf(val);
        hp[u] = (short)hv;
        lp[u] = (short)f2bf(val - bf2f(hv));
    }
    size_t off = ((size_t)(b * 64 + mm)) * 256 + h * 32 + g * 8;
    *(short8*)(ch + off) = hp;
    *(short8*)(cl + off) = lp;
}

extern "C" void kernel_launch(void* const* d_in, const int* in_sizes, int n_in,
                              void* d_out, int out_size, void* d_ws, size_t ws_size,
                              hipStream_t stream) {
    const float* emb = (const float*)d_in[0];
    const float* lib = (const float*)d_in[2];
    const float* pos = (const float*)d_in[3];
    const float* wq  = (const float*)d_in[4];
    const float* wk  = (const float*)d_in[5];
    const float* wv  = (const float*)d_in[6];
    const float* wo  = (const float*)d_in[7];
    float* out = (float*)d_out;

    float* ws   = (float*)d_ws;
    float* kbuf = ws;                          // 1,048,576 f
    float* vbuf = kbuf + 1048576;              // 1,048,576 f
    float* qbuf = vbuf + 1048576;              // 16,384 f
    ushort_t* xh   = (ushort_t*)(qbuf + 16384);// 1,048,576 us
    ushort_t* xl   = xh + 1048576;             // 1,048,576 us
    ushort_t* bt_h = xl + 1048576;             // 131,072 us ([512][256])
    ushort_t* bt_l = bt_h + 131072;            // 131,072 us
    ushort_t* wt_h = bt_l + 131072;            // 65,536 us ([256][256])
    ushort_t* wt_l = wt_h + 65536;             // 65,536 us
    ushort_t* ch   = wt_l + 65536;             // 131,072 us
    ushort_t* cl   = ch + 131072;              // 131,072 us   (~17.1 MB total)
    // part [64bh][8sq][64m][36] = 1,179,648 f == 4,718,592 B -> aliases
    // xh..bt_l exactly (dead after gemm_kv consumes them).
    float* part = (float*)xh;

    preproc_kernel<<<1889, 256, 0, stream>>>(emb, pos, wk, wv, wo, lib, wq,
            xh, xl, bt_h, bt_l, wt_h, wt_l, qbuf, (float4*)(out + 131072));

    gemm_direct_kernel<<<dim3(32, 8), 256, 0, stream>>>(xh, xl, bt_h, bt_l, kbuf, vbuf);

    attn_stage_kernel<<<dim3(64, 8), 256, 0, stream>>>(qbuf, kbuf, vbuf, part);

    attn_combine8_kernel<<<64, 256, 0, stream>>>(part, ch, cl);

    gemm_direct_kernel<<<dim3(4, 4), 256, 0, stream>>>(ch, cl, wt_h, wt_l, out, out);
}